// Round 4
// baseline (1343.745 us; speedup 1.0000x reference)
//
#include <hip/hip_runtime.h>
#include <hip/hip_bf16.h>

#define DIMC   128
#define HEADS  8
#define BATCH  8
#define XLEN   4096
#define NHEAD  64
#define EPSV   1e-5f
#define SCALEF 0.08838834764831845f   // 128^-0.5
#define XSPLIT_A 8
#define TX     64

typedef __attribute__((ext_vector_type(8))) short bf16x8;
typedef __attribute__((ext_vector_type(4))) float f32x4;
#define MFMA(a,b,c) __builtin_amdgcn_mfma_f32_16x16x32_bf16((a),(b),(c),0,0,0)

__device__ __forceinline__ short f2bf(float f) {
  union { float f; unsigned u; } v; v.f = f;
  return (short)((v.u + 0x7fffu + ((v.u >> 16) & 1u)) >> 16);
}
__device__ __forceinline__ float bf2f(short h) {
  union { unsigned u; float f; } v; v.u = ((unsigned)(unsigned short)h) << 16;
  return v.f;
}
__device__ __forceinline__ unsigned pk2(float a, float b) {
  return (unsigned)(unsigned short)f2bf(a) | ((unsigned)(unsigned short)f2bf(b) << 16);
}

// LDS fragment loads. Row-major bf16 tiles, XOR-swizzled: byte ^= (row&7)<<4.
// ldY: row stride 256 B ([64 rows][128 cols]); ldT: row stride 128 B ([128][64]).
__device__ __forceinline__ bf16x8 ldY(const short* Y, int row, int kcb) {
  return *(const bf16x8*)((const char*)Y + row*256 + (kcb ^ ((row&7)<<4)));
}
__device__ __forceinline__ bf16x8 ldT(const short* Y, int row, int kcb) {
  return *(const bf16x8*)((const char*)Y + row*128 + (kcb ^ ((row&7)<<4)));
}

// ---------------------------------------------------------------------------
// prep kernels
// ---------------------------------------------------------------------------
// fold BN into depthwise conv: dwf = dw*a, bfl = b - m*a  (p: 0=q,1=k,2=v)
__global__ void k_dw_prep(const float* dw0, const float* g0, const float* b0, const float* m0, const float* v0,
                          const float* dw1, const float* g1, const float* b1, const float* m1, const float* v1,
                          const float* dw2, const float* g2, const float* b2, const float* m2, const float* v2,
                          float* __restrict__ dwf, float* __restrict__ bfl) {
  int p = blockIdx.x, c = threadIdx.x;
  const float* dw = p == 0 ? dw0 : p == 1 ? dw1 : dw2;
  const float* g  = p == 0 ? g0  : p == 1 ? g1  : g2;
  const float* bb = p == 0 ? b0  : p == 1 ? b1  : b2;
  const float* m  = p == 0 ? m0  : p == 1 ? m1  : m2;
  const float* vv = p == 0 ? v0  : p == 1 ? v1  : v2;
  float a = g[c] * rsqrtf(vv[c] + EPSV);
  dwf[(p * DIMC + c) * 3 + 0] = dw[c * 3 + 0] * a;
  dwf[(p * DIMC + c) * 3 + 1] = dw[c * 3 + 1] * a;
  dwf[(p * DIMC + c) * 3 + 2] = dw[c * 3 + 2] * a;
  bfl[p * DIMC + c] = bb[c] - m[c] * a;
}

// gate fold: g_out[x][e] = sum_i q[x][i]*Gt[i][e] + c0[e]
__global__ void k_gate_prep(const float* __restrict__ gt_pw, const float* __restrict__ gt_dw,
                            const float* __restrict__ gt_g, const float* __restrict__ gt_b,
                            const float* __restrict__ gt_m, const float* __restrict__ gt_v,
                            float* __restrict__ Gt, float* __restrict__ c0) {
  int d = threadIdx.x;
  float s = 0.f;
  for (int i = 0; i < DIMC; ++i) {
    float a  = gt_g[i] * rsqrtf(gt_v[i] + EPSV);
    float w1 = gt_dw[i] * a;
    float w0 = gt_b[i] - gt_m[i] * a;
    float pw = gt_pw[d * DIMC + i];
    Gt[i * DIMC + d] = pw * w1;
    s += pw * w0;
  }
  c0[d] = s;
}

// Wg_h[c][e] = sum_d Wq_h[c][d]*Gt[d][e],  Wq_h[c][d] = q_pw[h*128+d][c]
__global__ void k_wg(const float* __restrict__ q_pw, const float* __restrict__ Gt,
                     float* __restrict__ WgF) {
  const int h = blockIdx.x, cb = blockIdx.y, t = threadIdx.x;
  const int c = cb * 16 + (t >> 4);
  const int e0 = (t & 15) * 8;
  float acc[8] = {0.f,0.f,0.f,0.f,0.f,0.f,0.f,0.f};
  for (int d = 0; d < DIMC; ++d) {
    float wq = q_pw[((size_t)(h * DIMC + d)) * DIMC + c];
    const float* gr = Gt + d * DIMC + e0;
    #pragma unroll
    for (int j = 0; j < 8; ++j) acc[j] += wq * gr[j];
  }
  float* out = WgF + ((size_t)h * DIMC + c) * DIMC + e0;
  #pragma unroll
  for (int j = 0; j < 8; ++j) out[j] = acc[j];
}

// pack B-frags (proj weights, hi/lo) and A-frags (out_w, hi/lo) in MFMA lane order
__global__ void k_pack(const float* __restrict__ q_pw, const float* __restrict__ k_pw,
                       const float* __restrict__ v_pw, const float* __restrict__ out_w,
                       short* __restrict__ Wpk, short* __restrict__ Opk) {
  const int blk = blockIdx.x, t = threadIdx.x;
  if (blk < 48) {             // proj B-frag: value = pw[h*128 + nt*16 + (l&15)][kt*32 + (l>>4)*8 + j]
    const int p = blk / 16, h = (blk / 2) & 7, hl = blk & 1;
    const float* pw = p == 0 ? q_pw : p == 1 ? k_pw : v_pw;
    short* dst = Wpk + (size_t)((p * 8 + h) * 2 + hl) * 16384;
    for (int s = t; s < 2048; s += 256) {
      const int l = s & 63, kt = (s >> 6) >> 3, nt = (s >> 6) & 7;
      const int o = h * DIMC + nt * 16 + (l & 15);
      const int cb = kt * 32 + (l >> 4) * 8;
      #pragma unroll
      for (int j = 0; j < 8; ++j) {
        float wv = pw[(size_t)o * DIMC + cb + j];
        short hi = f2bf(wv);
        dst[s * 8 + j] = (hl == 0) ? hi : f2bf(wv - bf2f(hi));
      }
    }
  } else {                    // out_w A-frag: value = out_w[mt*16 + (l&15)][h*128 + kt*32 + (l>>4)*8 + j]
    const int m = blk - 48, h = m >> 1, hl = m & 1;
    short* dst = Opk + (size_t)(h * 2 + hl) * 16384;
    for (int s = t; s < 2048; s += 256) {
      const int l = s & 63, mt = (s >> 6) >> 2, kt = (s >> 6) & 3;
      const int o = mt * 16 + (l & 15);
      const int ib = h * DIMC + kt * 32 + (l >> 4) * 8;
      #pragma unroll
      for (int j = 0; j < 8; ++j) {
        float wv = out_w[(size_t)o * (DIMC * HEADS) + ib + j];
        short hi = f2bf(wv);
        dst[s * 8 + j] = (hl == 0) ? hi : f2bf(wv - bf2f(hi));
      }
    }
  }
}

__global__ void k_gpack(const float* __restrict__ WgF, short* __restrict__ Gpk) {
  const int h = blockIdx.x, t = threadIdx.x;
  const float* src = WgF + (size_t)h * 16384;
  short* dst = Gpk + (size_t)h * 16384;
  for (int s = t; s < 2048; s += 256) {
    const int l = s & 63, kt = (s >> 6) >> 3, nt = (s >> 6) & 7;
    const int cb = kt * 32 + (l >> 4) * 8, e = nt * 16 + (l & 15);
    #pragma unroll
    for (int j = 0; j < 8; ++j) dst[s * 8 + j] = f2bf(src[(size_t)(cb + j) * DIMC + e]);
  }
}

// atomic-fallback path: pack kat (fp32, SCALE applied) -> frag bf16
__global__ void k_katpk(const float* __restrict__ kat, short* __restrict__ katpk) {
  const int n = blockIdx.x, t = threadIdx.x;
  const float* kn = kat + (size_t)n * 16384;
  short* dst = katpk + (size_t)n * 16384;
  for (int s = t; s < 2048; s += 256) {
    const int l = s & 63, kt = (s >> 6) >> 3, nt = (s >> 6) & 7;
    const int db = kt * 32 + (l >> 4) * 8, e = nt * 16 + (l & 15);
    #pragma unroll
    for (int j = 0; j < 8; ++j) dst[s * 8 + j] = f2bf(kn[(size_t)(db + j) * DIMC + e]);
  }
}

// partial path: sum XSPLIT_A partial kat tiles, scale, pack frags. grid(64)
__global__ __launch_bounds__(256) void k_red(const float* __restrict__ part,
                                             short* __restrict__ katpk) {
  __shared__ float sm[DIMC * DIMC];      // 64 KB
  const int n = blockIdx.x, t = threadIdx.x;
  for (int idx = t; idx < DIMC * DIMC; idx += 256) {
    float a = 0.f;
    #pragma unroll
    for (int s8 = 0; s8 < XSPLIT_A; ++s8)
      a += part[((size_t)(s8 * NHEAD + n)) * 16384 + idx];
    sm[idx] = a * SCALEF;
  }
  __syncthreads();
  short* dst = katpk + (size_t)n * 16384;
  for (int s = t; s < 2048; s += 256) {
    const int l = s & 63, kt = (s >> 6) >> 3, nt = (s >> 6) & 7;
    const int db = kt * 32 + (l >> 4) * 8, e = nt * 16 + (l & 15);
    #pragma unroll
    for (int j = 0; j < 8; ++j) dst[s * 8 + j] = f2bf(sm[(db + j) * DIMC + e]);
  }
}

// ---------------------------------------------------------------------------
// stage Y tiles: dwconv+BN for two projections -> swizzled bf16 LDS [64 x][128 c]
// ---------------------------------------------------------------------------
__device__ __forceinline__ void stage2(const float* __restrict__ x,
    const float* __restrict__ dwf, const float* __restrict__ bfl,
    int b, int xg0, int t, short* Y0, short* Y1, int p0, int p1)
{
  const int xl = t & 63, cg = t >> 6;
  const int xg = xg0 + xl;
  #pragma unroll
  for (int i = 0; i < 16; ++i) {
    const int c = 2 * (cg + 4 * i);
    float v0[2], v1[2];
    #pragma unroll
    for (int u = 0; u < 2; ++u) {
      const int cc = c + u;
      const float* xr = x + ((size_t)b * DIMC + cc) * XLEN + xg;
      float xm = (xg > 0) ? xr[-1] : 0.f;
      float xc = xr[0];
      float xp = (xg < XLEN - 1) ? xr[1] : 0.f;
      const float* d0 = dwf + (p0 * DIMC + cc) * 3;
      const float* d1 = dwf + (p1 * DIMC + cc) * 3;
      v0[u] = xm * d0[0] + xc * d0[1] + xp * d0[2] + bfl[p0 * DIMC + cc];
      v1[u] = xm * d1[0] + xc * d1[1] + xp * d1[2] + bfl[p1 * DIMC + cc];
    }
    const unsigned off = xl * 256 + ((c * 2) ^ ((xl & 7) << 4));
    *(unsigned*)((char*)Y0 + off) = pk2(v0[0], v0[1]);
    *(unsigned*)((char*)Y1 + off) = pk2(v1[0], v1[1]);
  }
}

// ---------------------------------------------------------------------------
// Kernel A: kat partial[xsplit][n][d][e] = sum_x q[n,x,d] * softmax_e(k[n,x,:])
// q,k recomputed from x (dwconv+BN fold + per-head pw GEMM, hi/lo bf16 MFMA).
// grid (8 x-splits, 64 n), 256 thr (4 waves).
// useAtomic=0: plain stores to part (no SCALE). useAtomic=1: atomicAdd to kat.
// ---------------------------------------------------------------------------
__global__ __launch_bounds__(256) void k_kat2(
    const float* __restrict__ x, const float* __restrict__ dwf,
    const float* __restrict__ bfl, const short* __restrict__ Wpk,
    float* __restrict__ part, float* __restrict__ kat, int useAtomic)
{
  __shared__ __align__(16) short Yq[TX * 128], Yk[TX * 128];
  __shared__ __align__(16) short QT[128 * TX], ST[128 * TX];
  const int t = threadIdx.x, w = t >> 6, l = t & 63;
  const int l15 = l & 15, lq = l >> 4;
  const int n = blockIdx.y, b = n >> 3, h = n & 7;
  const int xbase = blockIdx.x * (XLEN / XSPLIT_A);

  const short* WqHi = Wpk + (size_t)((0 * 8 + h) * 2 + 0) * 16384;
  const short* WqLo = Wpk + (size_t)((0 * 8 + h) * 2 + 1) * 16384;
  const short* WkHi = Wpk + (size_t)((1 * 8 + h) * 2 + 0) * 16384;
  const short* WkLo = Wpk + (size_t)((1 * 8 + h) * 2 + 1) * 16384;

  f32x4 ka[2][8];
  #pragma unroll
  for (int i = 0; i < 2; ++i)
    #pragma unroll
    for (int j = 0; j < 8; ++j) ka[i][j] = {0.f, 0.f, 0.f, 0.f};

  for (int ch = 0; ch < (XLEN / XSPLIT_A) / TX; ++ch) {
    __syncthreads();
    stage2(x, dwf, bfl, b, xbase + ch * TX, t, Yq, Yk, 0, 1);
    __syncthreads();

    // Q GEMM (weights hi+lo)
    f32x4 qa[8];
    #pragma unroll
    for (int j = 0; j < 8; ++j) qa[j] = {0.f, 0.f, 0.f, 0.f};
    #pragma unroll
    for (int kt = 0; kt < 4; ++kt) {
      bf16x8 a = ldY(Yq, w * 16 + l15, kt * 64 + lq * 16);
      #pragma unroll
      for (int nt = 0; nt < 8; ++nt) {
        bf16x8 bh = *(const bf16x8*)&WqHi[(kt * 8 + nt) * 512 + l * 8];
        bf16x8 bl = *(const bf16x8*)&WqLo[(kt * 8 + nt) * 512 + l * 8];
        qa[nt] = MFMA(a, bh, qa[nt]);
        qa[nt] = MFMA(a, bl, qa[nt]);
      }
    }
    // write Q^T[d][x]
    #pragma unroll
    for (int nt = 0; nt < 8; ++nt) {
      const int d = nt * 16 + l15;
      #pragma unroll
      for (int rp = 0; rp < 2; ++rp) {
        const int x2 = w * 16 + lq * 4 + rp * 2;
        *(unsigned*)((char*)QT + d * 128 + ((x2 * 2) ^ ((d & 7) << 4))) =
            pk2(qa[nt][rp * 2], qa[nt][rp * 2 + 1]);
      }
    }

    // K GEMM (weights hi+lo), reuse qa
    #pragma unroll
    for (int j = 0; j < 8; ++j) qa[j] = {0.f, 0.f, 0.f, 0.f};
    #pragma unroll
    for (int kt = 0; kt < 4; ++kt) {
      bf16x8 a = ldY(Yk, w * 16 + l15, kt * 64 + lq * 16);
      #pragma unroll
      for (int nt = 0; nt < 8; ++nt) {
        bf16x8 bh = *(const bf16x8*)&WkHi[(kt * 8 + nt) * 512 + l * 8];
        bf16x8 bl = *(const bf16x8*)&WkLo[(kt * 8 + nt) * 512 + l * 8];
        qa[nt] = MFMA(a, bh, qa[nt]);
        qa[nt] = MFMA(a, bl, qa[nt]);
      }
    }
    // in-register row softmax (row = x, spread over l15 lanes x 8 tiles)
    float inv[4];
    #pragma unroll
    for (int r = 0; r < 4; ++r) {
      float m = qa[0][r];
      #pragma unroll
      for (int nt = 1; nt < 8; ++nt) m = fmaxf(m, qa[nt][r]);
      m = fmaxf(m, __shfl_xor(m, 1)); m = fmaxf(m, __shfl_xor(m, 2));
      m = fmaxf(m, __shfl_xor(m, 4)); m = fmaxf(m, __shfl_xor(m, 8));
      float s = 0.f;
      #pragma unroll
      for (int nt = 0; nt < 8; ++nt) { float e = __expf(qa[nt][r] - m); qa[nt][r] = e; s += e; }
      s += __shfl_xor(s, 1); s += __shfl_xor(s, 2); s += __shfl_xor(s, 4); s += __shfl_xor(s, 8);
      inv[r] = 1.f / s;
    }
    // write S^T[e][x]
    #pragma unroll
    for (int nt = 0; nt < 8; ++nt) {
      const int e = nt * 16 + l15;
      #pragma unroll
      for (int rp = 0; rp < 2; ++rp) {
        const int x2 = w * 16 + lq * 4 + rp * 2;
        *(unsigned*)((char*)ST + e * 128 + ((x2 * 2) ^ ((e & 7) << 4))) =
            pk2(qa[nt][rp * 2] * inv[rp * 2], qa[nt][rp * 2 + 1] * inv[rp * 2 + 1]);
      }
    }
    __syncthreads();

    // kat accumulate: ka[mt][nt] += QT_A(d,x) x ST_B(x,e), K = 64
    #pragma unroll
    for (int kt2 = 0; kt2 < 2; ++kt2) {
      bf16x8 a0 = ldT(QT, w * 32 + l15,      kt2 * 64 + lq * 16);
      bf16x8 a1 = ldT(QT, w * 32 + 16 + l15, kt2 * 64 + lq * 16);
      #pragma unroll
      for (int nt = 0; nt < 8; ++nt) {
        bf16x8 bs = ldT(ST, nt * 16 + l15, kt2 * 64 + lq * 16);
        ka[0][nt] = MFMA(a0, bs, ka[0][nt]);
        ka[1][nt] = MFMA(a1, bs, ka[1][nt]);
      }
    }
  }
  if (!useAtomic) {
    float* dst = part + ((size_t)(blockIdx.x * NHEAD + n)) * 16384;
    #pragma unroll
    for (int mt = 0; mt < 2; ++mt)
      #pragma unroll
      for (int nt = 0; nt < 8; ++nt)
        #pragma unroll
        for (int r = 0; r < 4; ++r) {
          const int d = w * 32 + mt * 16 + lq * 4 + r;
          const int e = nt * 16 + l15;
          dst[d * DIMC + e] = ka[mt][nt][r];
        }
  } else {
    #pragma unroll
    for (int mt = 0; mt < 2; ++mt)
      #pragma unroll
      for (int nt = 0; nt < 8; ++nt)
        #pragma unroll
        for (int r = 0; r < 4; ++r) {
          const int d = w * 32 + mt * 16 + lq * 4 + r;
          const int e = nt * 16 + l15;
          atomicAdd(&kat[((size_t)n * DIMC + d) * DIMC + e], ka[mt][nt][r] * SCALEF);
        }
  }
}

// ---------------------------------------------------------------------------
// Kernel B: per 64-pos tile: recompute Yq,Yv; per head: V & gate GEMMs,
// v@kat, sigmoid-gate combine, final 1024->128 projection (accumulated).
// grid (64, 8), 256 thr.
// ---------------------------------------------------------------------------
__global__ __launch_bounds__(256) void k_out2(
    const float* __restrict__ x, const float* __restrict__ dwf,
    const float* __restrict__ bfl, const short* __restrict__ Wpk,
    const short* __restrict__ Gpk, const short* __restrict__ katpk,
    const short* __restrict__ Opk, const float* __restrict__ c0,
    const float* __restrict__ outb, float* __restrict__ outp)
{
  __shared__ __align__(16) short Yq[TX * 128], Yv[TX * 128];
  __shared__ __align__(16) short Vx[TX * 128], Tn[TX * 128];
  const int t = threadIdx.x, w = t >> 6, l = t & 63;
  const int l15 = l & 15, lq = l >> 4;
  const int b = blockIdx.y;
  const int x0 = blockIdx.x * TX;

  f32x4 oacc[2][4];
  #pragma unroll
  for (int i = 0; i < 2; ++i)
    #pragma unroll
    for (int j = 0; j < 4; ++j) oacc[i][j] = {0.f, 0.f, 0.f, 0.f};
  float c0v[8], obv[2][4];
  #pragma unroll
  for (int nt = 0; nt < 8; ++nt) c0v[nt] = c0[nt * 16 + l15];
  #pragma unroll
  for (int mt = 0; mt < 2; ++mt)
    #pragma unroll
    for (int r = 0; r < 4; ++r) obv[mt][r] = outb[w * 32 + mt * 16 + lq * 4 + r];

  stage2(x, dwf, bfl, b, x0, t, Yq, Yv, 0, 2);
  __syncthreads();

  for (int h = 0; h < HEADS; ++h) {
    const int n = b * HEADS + h;
    const short* WvHi = Wpk + (size_t)((2 * 8 + h) * 2 + 0) * 16384;
    const short* WvLo = Wpk + (size_t)((2 * 8 + h) * 2 + 1) * 16384;
    const short* Wg   = Gpk + (size_t)h * 16384;
    const short* Kp   = katpk + (size_t)n * 16384;

    // V GEMM (hi/lo) + gate GEMM (single)
    f32x4 va[8], ga[8];
    #pragma unroll
    for (int j = 0; j < 8; ++j) { va[j] = {0.f,0.f,0.f,0.f}; ga[j] = {0.f,0.f,0.f,0.f}; }
    #pragma unroll
    for (int kt = 0; kt < 4; ++kt) {
      bf16x8 aV = ldY(Yv, w * 16 + l15, kt * 64 + lq * 16);
      bf16x8 aQ = ldY(Yq, w * 16 + l15, kt * 64 + lq * 16);
      #pragma unroll
      for (int nt = 0; nt < 8; ++nt) {
        bf16x8 bh = *(const bf16x8*)&WvHi[(kt * 8 + nt) * 512 + l * 8];
        bf16x8 bl = *(const bf16x8*)&WvLo[(kt * 8 + nt) * 512 + l * 8];
        bf16x8 bg = *(const bf16x8*)&Wg[(kt * 8 + nt) * 512 + l * 8];
        va[nt] = MFMA(aV, bh, va[nt]);
        va[nt] = MFMA(aV, bl, va[nt]);
        ga[nt] = MFMA(aQ, bg, ga[nt]);
      }
    }
    // write V[x][d] (own wave strip -> no barrier needed)
    #pragma unroll
    for (int nt = 0; nt < 8; ++nt) {
      const int dd = nt * 16 + l15;
      #pragma unroll
      for (int r = 0; r < 4; ++r) {
        const int xr = w * 16 + lq * 4 + r;
        *(short*)((char*)Vx + xr * 256 + ((dd * 2) ^ ((xr & 7) << 4))) = f2bf(va[nt][r]);
      }
    }
    // KV GEMM: A = V[x][d] (own strip), B = kat frags
    f32x4 kv[8];
    #pragma unroll
    for (int j = 0; j < 8; ++j) kv[j] = {0.f, 0.f, 0.f, 0.f};
    #pragma unroll
    for (int kt = 0; kt < 4; ++kt) {
      bf16x8 aK = ldY(Vx, w * 16 + l15, kt * 64 + lq * 16);
      #pragma unroll
      for (int nt = 0; nt < 8; ++nt) {
        bf16x8 bk = *(const bf16x8*)&Kp[(kt * 8 + nt) * 512 + l * 8];
        kv[nt] = MFMA(aK, bk, kv[nt]);
      }
    }
    // combine: T = KV + sigmoid(GO + c0) * V  -> Tn[x][e]
    #pragma unroll
    for (int nt = 0; nt < 8; ++nt) {
      const int e = nt * 16 + l15;
      #pragma unroll
      for (int r = 0; r < 4; ++r) {
        const int xr = w * 16 + lq * 4 + r;
        float vv = bf2f(*(const short*)((const char*)Vx + xr * 256 + ((e * 2) ^ ((xr & 7) << 4))));
        float g = ga[nt][r] + c0v[nt];
        float sig = 1.f / (1.f + __expf(-g));
        *(short*)((char*)Tn + xr * 256 + ((e * 2) ^ ((xr & 7) << 4))) = f2bf(kv[nt][r] + sig * vv);
      }
    }
    __syncthreads();
    // final projection accumulate: oacc += out_w_h (hi/lo) x Tn
    const short* OHi = Opk + (size_t)(h * 2 + 0) * 16384;
    const short* OLo = Opk + (size_t)(h * 2 + 1) * 16384;
    #pragma unroll
    for (int kt = 0; kt < 4; ++kt) {
      bf16x8 a0h = *(const bf16x8*)&OHi[((w * 2 + 0) * 4 + kt) * 512 + l * 8];
      bf16x8 a1h = *(const bf16x8*)&OHi[((w * 2 + 1) * 4 + kt) * 512 + l * 8];
      bf16x8 a0l = *(const bf16x8*)&OLo[((w * 2 + 0) * 4 + kt) * 512 + l * 8];
      bf16x8 a1l = *(const bf16x8*)&OLo[((w * 2 + 1) * 4 + kt) * 512 + l * 8];
      #pragma unroll
      for (int nt4 = 0; nt4 < 4; ++nt4) {
        bf16x8 bt = ldY(Tn, nt4 * 16 + l15, kt * 64 + lq * 16);
        oacc[0][nt4] = MFMA(a0h, bt, oacc[0][nt4]);
        oacc[0][nt4] = MFMA(a0l, bt, oacc[0][nt4]);
        oacc[1][nt4] = MFMA(a1h, bt, oacc[1][nt4]);
        oacc[1][nt4] = MFMA(a1l, bt, oacc[1][nt4]);
      }
    }
    __syncthreads();
  }
  #pragma unroll
  for (int mt = 0; mt < 2; ++mt)
    #pragma unroll
    for (int nt4 = 0; nt4 < 4; ++nt4)
      #pragma unroll
      for (int r = 0; r < 4; ++r) {
        const int o = w * 32 + mt * 16 + lq * 4 + r;
        const int xx = x0 + nt4 * 16 + l15;
        outp[((size_t)b * DIMC + o) * XLEN + xx] = oacc[mt][nt4][r] + obv[mt][r];
      }
}

// ---------------------------------------------------------------------------
extern "C" void kernel_launch(void* const* d_in, const int* in_sizes, int n_in,
                              void* d_out, int out_size, void* d_ws, size_t ws_size,
                              hipStream_t stream) {
  (void)in_sizes; (void)n_in; (void)out_size;
  const float* x = (const float*)d_in[0];
  // q: 1..6, k: 7..12, v: 13..18 (dw,g,b,m,v,pw), gt: 19..24, out_w:25, out_b:26

  char* ws = (char*)d_ws;
  short* katpk = (short*)(ws);                       // 2 MB
  short* Wpk   = (short*)(ws + 2097152);             // 1.5 MB (q,k,v hi/lo B-frags)
  short* Opk   = (short*)(ws + 3670016);             // 512 KB (out_w hi/lo A-frags)
  short* Gpk   = (short*)(ws + 4194304);             // 256 KB (Wg B-frags)
  float* WgF   = (float*)(ws + 4456448);             // 512 KB
  float* Gt    = (float*)(ws + 4980736);             // 64 KB
  float* c0    = (float*)(ws + 5046272);             // 512 B
  float* dwf   = (float*)(ws + 5046784);             // 4.6 KB
  float* bfl   = (float*)(ws + 5051392);             // 1.5 KB
  float* kat   = (float*)(ws + 5052928);             // 4 MB (atomic fallback)
  float* part  = (float*)(ws + 9247232);             // 33.5 MB (partial path)
  constexpr size_t WS_NEED_PART = 9247232 + (size_t)XSPLIT_A * NHEAD * 16384 * 4;
  const int useAtomic = (ws_size < WS_NEED_PART) ? 1 : 0;

  k_dw_prep<<<3, 128, 0, stream>>>(
      (const float*)d_in[1],  (const float*)d_in[2],  (const float*)d_in[3],
      (const float*)d_in[4],  (const float*)d_in[5],
      (const float*)d_in[7],  (const float*)d_in[8],  (const float*)d_in[9],
      (const float*)d_in[10], (const float*)d_in[11],
      (const float*)d_in[13], (const float*)d_in[14], (const float*)d_in[15],
      (const float*)d_in[16], (const float*)d_in[17], dwf, bfl);

  k_gate_prep<<<1, 128, 0, stream>>>(
      (const float*)d_in[24], (const float*)d_in[19], (const float*)d_in[20],
      (const float*)d_in[21], (const float*)d_in[22], (const float*)d_in[23], Gt, c0);

  k_wg<<<dim3(8, 8), 256, 0, stream>>>((const float*)d_in[6], Gt, WgF);

  k_pack<<<64, 256, 0, stream>>>((const float*)d_in[6], (const float*)d_in[12],
                                 (const float*)d_in[18], (const float*)d_in[25],
                                 Wpk, Opk);
  k_gpack<<<8, 256, 0, stream>>>(WgF, Gpk);

  if (useAtomic) {
    hipMemsetAsync(kat, 0, (size_t)NHEAD * DIMC * DIMC * 4, stream);
    k_kat2<<<dim3(XSPLIT_A, NHEAD), 256, 0, stream>>>(x, dwf, bfl, Wpk, part, kat, 1);
    k_katpk<<<64, 256, 0, stream>>>(kat, katpk);
  } else {
    k_kat2<<<dim3(XSPLIT_A, NHEAD), 256, 0, stream>>>(x, dwf, bfl, Wpk, part, kat, 0);
    k_red<<<64, 256, 0, stream>>>(part, katpk);
  }
  k_out2<<<dim3(XLEN / TX, BATCH), 256, 0, stream>>>(x, dwf, bfl, Wpk, Gpk, katpk,
                                                     Opk, c0, (const float*)d_in[26],
                                                     (float*)d_out);
}

// Round 5
// 1301.777 us; speedup vs baseline: 1.0322x; 1.0322x over previous
//
#include <hip/hip_runtime.h>
#include <hip/hip_bf16.h>

#define DIMC   128
#define HEADS  8
#define BATCH  8
#define XLEN   4096
#define NHEAD  64
#define EPSV   1e-5f
#define SCALEF 0.08838834764831845f   // 128^-0.5
#define TX     64

typedef __attribute__((ext_vector_type(8))) short bf16x8;
typedef __attribute__((ext_vector_type(4))) float f32x4;
#define MFMA(a,b,c) __builtin_amdgcn_mfma_f32_16x16x32_bf16((a),(b),(c),0,0,0)

__device__ __forceinline__ short f2bf(float f) {
  union { float f; unsigned u; } v; v.f = f;
  return (short)((v.u + 0x7fffu + ((v.u >> 16) & 1u)) >> 16);
}
__device__ __forceinline__ float bf2f(short h) {
  union { unsigned u; float f; } v; v.u = ((unsigned)(unsigned short)h) << 16;
  return v.f;
}
__device__ __forceinline__ unsigned pk2(float a, float b) {
  return (unsigned)(unsigned short)f2bf(a) | ((unsigned)(unsigned short)f2bf(b) << 16);
}

// LDS fragment loads. Row-major bf16 tiles, XOR-swizzled: byte ^= (row&7)<<4.
// ldY: row stride 256 B ([64 rows][128 cols]); ldT: row stride 128 B ([128][64]).
__device__ __forceinline__ bf16x8 ldY(const short* Y, int row, int kcb) {
  return *(const bf16x8*)((const char*)Y + row*256 + (kcb ^ ((row&7)<<4)));
}
__device__ __forceinline__ bf16x8 ldT(const short* Y, int row, int kcb) {
  return *(const bf16x8*)((const char*)Y + row*128 + (kcb ^ ((row&7)<<4)));
}

// ---------------------------------------------------------------------------
// prep kernels
// ---------------------------------------------------------------------------
// fold BN into depthwise conv: dwf = dw*a, bfl = b - m*a  (p: 0=q,1=k,2=v)
__global__ void k_dw_prep(const float* dw0, const float* g0, const float* b0, const float* m0, const float* v0,
                          const float* dw1, const float* g1, const float* b1, const float* m1, const float* v1,
                          const float* dw2, const float* g2, const float* b2, const float* m2, const float* v2,
                          float* __restrict__ dwf, float* __restrict__ bfl) {
  int p = blockIdx.x, c = threadIdx.x;
  const float* dw = p == 0 ? dw0 : p == 1 ? dw1 : dw2;
  const float* g  = p == 0 ? g0  : p == 1 ? g1  : g2;
  const float* bb = p == 0 ? b0  : p == 1 ? b1  : b2;
  const float* m  = p == 0 ? m0  : p == 1 ? m1  : m2;
  const float* vv = p == 0 ? v0  : p == 1 ? v1  : v2;
  float a = g[c] * rsqrtf(vv[c] + EPSV);
  dwf[(p * DIMC + c) * 3 + 0] = dw[c * 3 + 0] * a;
  dwf[(p * DIMC + c) * 3 + 1] = dw[c * 3 + 1] * a;
  dwf[(p * DIMC + c) * 3 + 2] = dw[c * 3 + 2] * a;
  bfl[p * DIMC + c] = bb[c] - m[c] * a;
}

// gate fold: g_out[x][e] = sum_i q[x][i]*Gt[i][e] + c0[e]
__global__ void k_gate_prep(const float* __restrict__ gt_pw, const float* __restrict__ gt_dw,
                            const float* __restrict__ gt_g, const float* __restrict__ gt_b,
                            const float* __restrict__ gt_m, const float* __restrict__ gt_v,
                            float* __restrict__ Gt, float* __restrict__ c0) {
  int d = threadIdx.x;
  float s = 0.f;
  for (int i = 0; i < DIMC; ++i) {
    float a  = gt_g[i] * rsqrtf(gt_v[i] + EPSV);
    float w1 = gt_dw[i] * a;
    float w0 = gt_b[i] - gt_m[i] * a;
    float pw = gt_pw[d * DIMC + i];
    Gt[i * DIMC + d] = pw * w1;
    s += pw * w0;
  }
  c0[d] = s;
}

// Wg_h[c][e] = sum_d Wq_h[c][d]*Gt[d][e],  Wq_h[c][d] = q_pw[h*128+d][c]
__global__ void k_wg(const float* __restrict__ q_pw, const float* __restrict__ Gt,
                     float* __restrict__ WgF) {
  const int h = blockIdx.x, cb = blockIdx.y, t = threadIdx.x;
  const int c = cb * 16 + (t >> 4);
  const int e0 = (t & 15) * 8;
  float acc[8] = {0.f,0.f,0.f,0.f,0.f,0.f,0.f,0.f};
  for (int d = 0; d < DIMC; ++d) {
    float wq = q_pw[((size_t)(h * DIMC + d)) * DIMC + c];
    const float* gr = Gt + d * DIMC + e0;
    #pragma unroll
    for (int j = 0; j < 8; ++j) acc[j] += wq * gr[j];
  }
  float* out = WgF + ((size_t)h * DIMC + c) * DIMC + e0;
  #pragma unroll
  for (int j = 0; j < 8; ++j) out[j] = acc[j];
}

// pack B-frags (proj weights, hi/lo) and A-frags (out_w, hi/lo) in MFMA lane order
__global__ void k_pack(const float* __restrict__ q_pw, const float* __restrict__ k_pw,
                       const float* __restrict__ v_pw, const float* __restrict__ out_w,
                       short* __restrict__ Wpk, short* __restrict__ Opk) {
  const int blk = blockIdx.x, t = threadIdx.x;
  if (blk < 48) {             // proj B-frag: value = pw[h*128 + nt*16 + (l&15)][kt*32 + (l>>4)*8 + j]
    const int p = blk / 16, h = (blk / 2) & 7, hl = blk & 1;
    const float* pw = p == 0 ? q_pw : p == 1 ? k_pw : v_pw;
    short* dst = Wpk + (size_t)((p * 8 + h) * 2 + hl) * 16384;
    for (int s = t; s < 2048; s += 256) {
      const int l = s & 63, kt = (s >> 6) >> 3, nt = (s >> 6) & 7;
      const int o = h * DIMC + nt * 16 + (l & 15);
      const int cb = kt * 32 + (l >> 4) * 8;
      #pragma unroll
      for (int j = 0; j < 8; ++j) {
        float wv = pw[(size_t)o * DIMC + cb + j];
        short hi = f2bf(wv);
        dst[s * 8 + j] = (hl == 0) ? hi : f2bf(wv - bf2f(hi));
      }
    }
  } else {                    // out_w A-frag: value = out_w[mt*16 + (l&15)][h*128 + kt*32 + (l>>4)*8 + j]
    const int m = blk - 48, h = m >> 1, hl = m & 1;
    short* dst = Opk + (size_t)(h * 2 + hl) * 16384;
    for (int s = t; s < 2048; s += 256) {
      const int l = s & 63, mt = (s >> 6) >> 2, kt = (s >> 6) & 3;
      const int o = mt * 16 + (l & 15);
      const int ib = h * DIMC + kt * 32 + (l >> 4) * 8;
      #pragma unroll
      for (int j = 0; j < 8; ++j) {
        float wv = out_w[(size_t)o * (DIMC * HEADS) + ib + j];
        short hi = f2bf(wv);
        dst[s * 8 + j] = (hl == 0) ? hi : f2bf(wv - bf2f(hi));
      }
    }
  }
}

__global__ void k_gpack(const float* __restrict__ WgF, short* __restrict__ Gpk) {
  const int h = blockIdx.x, t = threadIdx.x;
  const float* src = WgF + (size_t)h * 16384;
  short* dst = Gpk + (size_t)h * 16384;
  for (int s = t; s < 2048; s += 256) {
    const int l = s & 63, kt = (s >> 6) >> 3, nt = (s >> 6) & 7;
    const int cb = kt * 32 + (l >> 4) * 8, e = nt * 16 + (l & 15);
    #pragma unroll
    for (int j = 0; j < 8; ++j) dst[s * 8 + j] = f2bf(src[(size_t)(cb + j) * DIMC + e]);
  }
}

// atomic-fallback path: pack kat (fp32, SCALE applied) -> frag bf16
__global__ void k_katpk(const float* __restrict__ kat, short* __restrict__ katpk) {
  const int n = blockIdx.x, t = threadIdx.x;
  const float* kn = kat + (size_t)n * 16384;
  short* dst = katpk + (size_t)n * 16384;
  for (int s = t; s < 2048; s += 256) {
    const int l = s & 63, kt = (s >> 6) >> 3, nt = (s >> 6) & 7;
    const int db = kt * 32 + (l >> 4) * 8, e = nt * 16 + (l & 15);
    #pragma unroll
    for (int j = 0; j < 8; ++j) dst[s * 8 + j] = f2bf(kn[(size_t)(db + j) * DIMC + e]);
  }
}

// partial path: sum `splits` bf16 partial kat tiles, scale, pack frags. grid(64)
__global__ __launch_bounds__(256) void k_red(const short* __restrict__ part16,
                                             short* __restrict__ katpk, int splits) {
  __shared__ float sm[DIMC * DIMC];      // 64 KB
  const int n = blockIdx.x, t = threadIdx.x;
  for (int i0 = t * 8; i0 < DIMC * DIMC; i0 += 256 * 8) {
    float a[8] = {0.f,0.f,0.f,0.f,0.f,0.f,0.f,0.f};
    for (int s8 = 0; s8 < splits; ++s8) {
      bf16x8 pv = *(const bf16x8*)&part16[((size_t)(s8 * NHEAD + n)) * 16384 + i0];
      #pragma unroll
      for (int j = 0; j < 8; ++j) a[j] += bf2f(pv[j]);
    }
    #pragma unroll
    for (int j = 0; j < 8; ++j) sm[i0 + j] = a[j] * SCALEF;
  }
  __syncthreads();
  short* dst = katpk + (size_t)n * 16384;
  for (int s = t; s < 2048; s += 256) {
    const int l = s & 63, kt = (s >> 6) >> 3, nt = (s >> 6) & 7;
    const int db = kt * 32 + (l >> 4) * 8, e = nt * 16 + (l & 15);
    #pragma unroll
    for (int j = 0; j < 8; ++j) dst[s * 8 + j] = f2bf(sm[(db + j) * DIMC + e]);
  }
}

// ---------------------------------------------------------------------------
// stage Y tiles: dwconv+BN for two projections -> swizzled bf16 LDS [64 x][128 c]
// ---------------------------------------------------------------------------
__device__ __forceinline__ void stage2(const float* __restrict__ x,
    const float* __restrict__ dwf, const float* __restrict__ bfl,
    int b, int xg0, int t, short* Y0, short* Y1, int p0, int p1)
{
  const int xl = t & 63, cg = t >> 6;
  const int xg = xg0 + xl;
  #pragma unroll
  for (int i = 0; i < 16; ++i) {
    const int c = 2 * (cg + 4 * i);
    float v0[2], v1[2];
    #pragma unroll
    for (int u = 0; u < 2; ++u) {
      const int cc = c + u;
      const float* xr = x + ((size_t)b * DIMC + cc) * XLEN + xg;
      float xm = (xg > 0) ? xr[-1] : 0.f;
      float xc = xr[0];
      float xp = (xg < XLEN - 1) ? xr[1] : 0.f;
      const float* d0 = dwf + (p0 * DIMC + cc) * 3;
      const float* d1 = dwf + (p1 * DIMC + cc) * 3;
      v0[u] = xm * d0[0] + xc * d0[1] + xp * d0[2] + bfl[p0 * DIMC + cc];
      v1[u] = xm * d1[0] + xc * d1[1] + xp * d1[2] + bfl[p1 * DIMC + cc];
    }
    const unsigned off = xl * 256 + ((c * 2) ^ ((xl & 7) << 4));
    *(unsigned*)((char*)Y0 + off) = pk2(v0[0], v0[1]);
    *(unsigned*)((char*)Y1 + off) = pk2(v1[0], v1[1]);
  }
}

// ---------------------------------------------------------------------------
// Kernel A: kat partial[split][n][d][e] = sum_x q[n,x,d] * softmax_e(k[n,x,:])
// q,k recomputed from x (dwconv+BN fold + per-head pw GEMM, hi/lo bf16 MFMA).
// grid (splits, 64 n), 256 thr (4 waves).
// useAtomic=0: bf16 stores to part16 (no SCALE). useAtomic=1: atomicAdd to kat.
// ---------------------------------------------------------------------------
__global__ __launch_bounds__(256) void k_kat2(
    const float* __restrict__ x, const float* __restrict__ dwf,
    const float* __restrict__ bfl, const short* __restrict__ Wpk,
    short* __restrict__ part16, float* __restrict__ kat, int useAtomic)
{
  __shared__ __align__(16) short Yq[TX * 128], Yk[TX * 128];
  __shared__ __align__(16) short QT[128 * TX], ST[128 * TX];
  const int t = threadIdx.x, w = t >> 6, l = t & 63;
  const int l15 = l & 15, lq = l >> 4;
  const int n = blockIdx.y, b = n >> 3, h = n & 7;
  const int xspan = XLEN / gridDim.x;
  const int xbase = blockIdx.x * xspan;
  const int nchunk = xspan / TX;

  const short* WqHi = Wpk + (size_t)((0 * 8 + h) * 2 + 0) * 16384;
  const short* WqLo = Wpk + (size_t)((0 * 8 + h) * 2 + 1) * 16384;
  const short* WkHi = Wpk + (size_t)((1 * 8 + h) * 2 + 0) * 16384;
  const short* WkLo = Wpk + (size_t)((1 * 8 + h) * 2 + 1) * 16384;

  f32x4 ka[2][8];
  #pragma unroll
  for (int i = 0; i < 2; ++i)
    #pragma unroll
    for (int j = 0; j < 8; ++j) ka[i][j] = {0.f, 0.f, 0.f, 0.f};

  for (int ch = 0; ch < nchunk; ++ch) {
    __syncthreads();
    stage2(x, dwf, bfl, b, xbase + ch * TX, t, Yq, Yk, 0, 1);
    __syncthreads();

    // Q GEMM (weights hi+lo)
    f32x4 qa[8];
    #pragma unroll
    for (int j = 0; j < 8; ++j) qa[j] = {0.f, 0.f, 0.f, 0.f};
    #pragma unroll
    for (int kt = 0; kt < 4; ++kt) {
      bf16x8 a = ldY(Yq, w * 16 + l15, kt * 64 + lq * 16);
      #pragma unroll
      for (int nt = 0; nt < 8; ++nt) {
        bf16x8 bh = *(const bf16x8*)&WqHi[(kt * 8 + nt) * 512 + l * 8];
        bf16x8 bl = *(const bf16x8*)&WqLo[(kt * 8 + nt) * 512 + l * 8];
        qa[nt] = MFMA(a, bh, qa[nt]);
        qa[nt] = MFMA(a, bl, qa[nt]);
      }
    }
    // write Q^T[d][x]
    #pragma unroll
    for (int nt = 0; nt < 8; ++nt) {
      const int d = nt * 16 + l15;
      #pragma unroll
      for (int rp = 0; rp < 2; ++rp) {
        const int x2 = w * 16 + lq * 4 + rp * 2;
        *(unsigned*)((char*)QT + d * 128 + ((x2 * 2) ^ ((d & 7) << 4))) =
            pk2(qa[nt][rp * 2], qa[nt][rp * 2 + 1]);
      }
    }

    // K GEMM (weights hi+lo), reuse qa
    #pragma unroll
    for (int j = 0; j < 8; ++j) qa[j] = {0.f, 0.f, 0.f, 0.f};
    #pragma unroll
    for (int kt = 0; kt < 4; ++kt) {
      bf16x8 a = ldY(Yk, w * 16 + l15, kt * 64 + lq * 16);
      #pragma unroll
      for (int nt = 0; nt < 8; ++nt) {
        bf16x8 bh = *(const bf16x8*)&WkHi[(kt * 8 + nt) * 512 + l * 8];
        bf16x8 bl = *(const bf16x8*)&WkLo[(kt * 8 + nt) * 512 + l * 8];
        qa[nt] = MFMA(a, bh, qa[nt]);
        qa[nt] = MFMA(a, bl, qa[nt]);
      }
    }
    // in-register row softmax (row = x, spread over l15 lanes x 8 tiles)
    float inv[4];
    #pragma unroll
    for (int r = 0; r < 4; ++r) {
      float m = qa[0][r];
      #pragma unroll
      for (int nt = 1; nt < 8; ++nt) m = fmaxf(m, qa[nt][r]);
      m = fmaxf(m, __shfl_xor(m, 1)); m = fmaxf(m, __shfl_xor(m, 2));
      m = fmaxf(m, __shfl_xor(m, 4)); m = fmaxf(m, __shfl_xor(m, 8));
      float s = 0.f;
      #pragma unroll
      for (int nt = 0; nt < 8; ++nt) { float e = __expf(qa[nt][r] - m); qa[nt][r] = e; s += e; }
      s += __shfl_xor(s, 1); s += __shfl_xor(s, 2); s += __shfl_xor(s, 4); s += __shfl_xor(s, 8);
      inv[r] = 1.f / s;
    }
    // write S^T[e][x]
    #pragma unroll
    for (int nt = 0; nt < 8; ++nt) {
      const int e = nt * 16 + l15;
      #pragma unroll
      for (int rp = 0; rp < 2; ++rp) {
        const int x2 = w * 16 + lq * 4 + rp * 2;
        *(unsigned*)((char*)ST + e * 128 + ((x2 * 2) ^ ((e & 7) << 4))) =
            pk2(qa[nt][rp * 2] * inv[rp * 2], qa[nt][rp * 2 + 1] * inv[rp * 2 + 1]);
      }
    }
    __syncthreads();

    // kat accumulate: ka[mt][nt] += QT_A(d,x) x ST_B(x,e), K = 64
    #pragma unroll
    for (int kt2 = 0; kt2 < 2; ++kt2) {
      bf16x8 a0 = ldT(QT, w * 32 + l15,      kt2 * 64 + lq * 16);
      bf16x8 a1 = ldT(QT, w * 32 + 16 + l15, kt2 * 64 + lq * 16);
      #pragma unroll
      for (int nt = 0; nt < 8; ++nt) {
        bf16x8 bs = ldT(ST, nt * 16 + l15, kt2 * 64 + lq * 16);
        ka[0][nt] = MFMA(a0, bs, ka[0][nt]);
        ka[1][nt] = MFMA(a1, bs, ka[1][nt]);
      }
    }
  }
  if (!useAtomic) {
    short* dst = part16 + ((size_t)(blockIdx.x * NHEAD + n)) * 16384;
    #pragma unroll
    for (int mt = 0; mt < 2; ++mt)
      #pragma unroll
      for (int nt = 0; nt < 8; ++nt)
        #pragma unroll
        for (int r = 0; r < 4; ++r) {
          const int d = w * 32 + mt * 16 + lq * 4 + r;
          const int e = nt * 16 + l15;
          dst[d * DIMC + e] = f2bf(ka[mt][nt][r]);
        }
  } else {
    #pragma unroll
    for (int mt = 0; mt < 2; ++mt)
      #pragma unroll
      for (int nt = 0; nt < 8; ++nt)
        #pragma unroll
        for (int r = 0; r < 4; ++r) {
          const int d = w * 32 + mt * 16 + lq * 4 + r;
          const int e = nt * 16 + l15;
          atomicAdd(&kat[((size_t)n * DIMC + d) * DIMC + e], ka[mt][nt][r] * SCALEF);
        }
  }
}

// ---------------------------------------------------------------------------
// Kernel B: per 64-pos tile: recompute Yq,Yv; per head: V & gate GEMMs,
// v@kat, sigmoid-gate combine, final 1024->128 projection (accumulated).
// grid (64, 8), 256 thr.
// ---------------------------------------------------------------------------
__global__ __launch_bounds__(256) void k_out2(
    const float* __restrict__ x, const float* __restrict__ dwf,
    const float* __restrict__ bfl, const short* __restrict__ Wpk,
    const short* __restrict__ Gpk, const short* __restrict__ katpk,
    const short* __restrict__ Opk, const float* __restrict__ c0,
    const float* __restrict__ outb, float* __restrict__ outp)
{
  __shared__ __align__(16) short Yq[TX * 128], Yv[TX * 128];
  __shared__ __align__(16) short Vx[TX * 128], Tn[TX * 128];
  const int t = threadIdx.x, w = t >> 6, l = t & 63;
  const int l15 = l & 15, lq = l >> 4;
  const int b = blockIdx.y;
  const int x0 = blockIdx.x * TX;

  f32x4 oacc[2][4];
  #pragma unroll
  for (int i = 0; i < 2; ++i)
    #pragma unroll
    for (int j = 0; j < 4; ++j) oacc[i][j] = {0.f, 0.f, 0.f, 0.f};
  float c0v[8], obv[2][4];
  #pragma unroll
  for (int nt = 0; nt < 8; ++nt) c0v[nt] = c0[nt * 16 + l15];
  #pragma unroll
  for (int mt = 0; mt < 2; ++mt)
    #pragma unroll
    for (int r = 0; r < 4; ++r) obv[mt][r] = outb[w * 32 + mt * 16 + lq * 4 + r];

  stage2(x, dwf, bfl, b, x0, t, Yq, Yv, 0, 2);
  __syncthreads();

  for (int h = 0; h < HEADS; ++h) {
    const int n = b * HEADS + h;
    const short* WvHi = Wpk + (size_t)((2 * 8 + h) * 2 + 0) * 16384;
    const short* WvLo = Wpk + (size_t)((2 * 8 + h) * 2 + 1) * 16384;
    const short* Wg   = Gpk + (size_t)h * 16384;
    const short* Kp   = katpk + (size_t)n * 16384;

    // V GEMM (hi/lo) + gate GEMM (single)
    f32x4 va[8], ga[8];
    #pragma unroll
    for (int j = 0; j < 8; ++j) { va[j] = {0.f,0.f,0.f,0.f}; ga[j] = {0.f,0.f,0.f,0.f}; }
    #pragma unroll
    for (int kt = 0; kt < 4; ++kt) {
      bf16x8 aV = ldY(Yv, w * 16 + l15, kt * 64 + lq * 16);
      bf16x8 aQ = ldY(Yq, w * 16 + l15, kt * 64 + lq * 16);
      #pragma unroll
      for (int nt = 0; nt < 8; ++nt) {
        bf16x8 bh = *(const bf16x8*)&WvHi[(kt * 8 + nt) * 512 + l * 8];
        bf16x8 bl = *(const bf16x8*)&WvLo[(kt * 8 + nt) * 512 + l * 8];
        bf16x8 bg = *(const bf16x8*)&Wg[(kt * 8 + nt) * 512 + l * 8];
        va[nt] = MFMA(aV, bh, va[nt]);
        va[nt] = MFMA(aV, bl, va[nt]);
        ga[nt] = MFMA(aQ, bg, ga[nt]);
      }
    }
    // write V[x][d] (own wave strip -> no barrier needed)
    #pragma unroll
    for (int nt = 0; nt < 8; ++nt) {
      const int dd = nt * 16 + l15;
      #pragma unroll
      for (int r = 0; r < 4; ++r) {
        const int xr = w * 16 + lq * 4 + r;
        *(short*)((char*)Vx + xr * 256 + ((dd * 2) ^ ((xr & 7) << 4))) = f2bf(va[nt][r]);
      }
    }
    // KV GEMM: A = V[x][d] (own strip), B = kat frags
    f32x4 kv[8];
    #pragma unroll
    for (int j = 0; j < 8; ++j) kv[j] = {0.f, 0.f, 0.f, 0.f};
    #pragma unroll
    for (int kt = 0; kt < 4; ++kt) {
      bf16x8 aK = ldY(Vx, w * 16 + l15, kt * 64 + lq * 16);
      #pragma unroll
      for (int nt = 0; nt < 8; ++nt) {
        bf16x8 bk = *(const bf16x8*)&Kp[(kt * 8 + nt) * 512 + l * 8];
        kv[nt] = MFMA(aK, bk, kv[nt]);
      }
    }
    // combine: T = KV + sigmoid(GO + c0) * V  -> Tn[x][e]
    #pragma unroll
    for (int nt = 0; nt < 8; ++nt) {
      const int e = nt * 16 + l15;
      #pragma unroll
      for (int r = 0; r < 4; ++r) {
        const int xr = w * 16 + lq * 4 + r;
        float vv = bf2f(*(const short*)((const char*)Vx + xr * 256 + ((e * 2) ^ ((xr & 7) << 4))));
        float g = ga[nt][r] + c0v[nt];
        float sig = 1.f / (1.f + __expf(-g));
        *(short*)((char*)Tn + xr * 256 + ((e * 2) ^ ((xr & 7) << 4))) = f2bf(kv[nt][r] + sig * vv);
      }
    }
    __syncthreads();
    // final projection accumulate: oacc += out_w_h (hi/lo) x Tn
    const short* OHi = Opk + (size_t)(h * 2 + 0) * 16384;
    const short* OLo = Opk + (size_t)(h * 2 + 1) * 16384;
    #pragma unroll
    for (int kt = 0; kt < 4; ++kt) {
      bf16x8 a0h = *(const bf16x8*)&OHi[((w * 2 + 0) * 4 + kt) * 512 + l * 8];
      bf16x8 a1h = *(const bf16x8*)&OHi[((w * 2 + 1) * 4 + kt) * 512 + l * 8];
      bf16x8 a0l = *(const bf16x8*)&OLo[((w * 2 + 0) * 4 + kt) * 512 + l * 8];
      bf16x8 a1l = *(const bf16x8*)&OLo[((w * 2 + 1) * 4 + kt) * 512 + l * 8];
      #pragma unroll
      for (int nt4 = 0; nt4 < 4; ++nt4) {
        bf16x8 bt = ldY(Tn, nt4 * 16 + l15, kt * 64 + lq * 16);
        oacc[0][nt4] = MFMA(a0h, bt, oacc[0][nt4]);
        oacc[0][nt4] = MFMA(a0l, bt, oacc[0][nt4]);
        oacc[1][nt4] = MFMA(a1h, bt, oacc[1][nt4]);
        oacc[1][nt4] = MFMA(a1l, bt, oacc[1][nt4]);
      }
    }
    __syncthreads();
  }
  #pragma unroll
  for (int mt = 0; mt < 2; ++mt)
    #pragma unroll
    for (int nt4 = 0; nt4 < 4; ++nt4)
      #pragma unroll
      for (int r = 0; r < 4; ++r) {
        const int o = w * 32 + mt * 16 + lq * 4 + r;
        const int xx = x0 + nt4 * 16 + l15;
        outp[((size_t)b * DIMC + o) * XLEN + xx] = oacc[mt][nt4][r] + obv[mt][r];
      }
}

// ---------------------------------------------------------------------------
extern "C" void kernel_launch(void* const* d_in, const int* in_sizes, int n_in,
                              void* d_out, int out_size, void* d_ws, size_t ws_size,
                              hipStream_t stream) {
  (void)in_sizes; (void)n_in; (void)out_size;
  const float* x = (const float*)d_in[0];
  // q: 1..6, k: 7..12, v: 13..18 (dw,g,b,m,v,pw), gt: 19..24, out_w:25, out_b:26

  char* ws = (char*)d_ws;
  short* katpk = (short*)(ws);                       // 2 MB
  short* Wpk   = (short*)(ws + 2097152);             // 1.5 MB (q,k,v hi/lo B-frags)
  short* Opk   = (short*)(ws + 3670016);             // 512 KB (out_w hi/lo A-frags)
  short* Gpk   = (short*)(ws + 4194304);             // 256 KB (Wg B-frags)
  float* WgF   = (float*)(ws + 4456448);             // 512 KB
  float* Gt    = (float*)(ws + 4980736);             // 64 KB
  float* c0    = (float*)(ws + 5046272);             // 512 B
  float* dwf   = (float*)(ws + 5046784);             // 4.6 KB
  float* bfl   = (float*)(ws + 5051392);             // 1.5 KB
  // union region at 5,052,928: bf16 partials (splits x 64 x 128 x 128 x 2B)
  // OR fp32 kat (4 MB, atomic last-resort).
  constexpr size_t BASE = 5052928;
  short* part16 = (short*)(ws + BASE);
  float* kat    = (float*)(ws + BASE);
  constexpr size_t PART1 = (size_t)NHEAD * 16384 * 2;  // 2 MB per split
  // adaptive split count: largest in {8,4,2} that fits; rounds 3/4 prove
  // ws_size >= BASE + 2*PART1 (9,247,232 B), so splits>=2 always engages.
  int splits = 0;
  if      (ws_size >= BASE + 8 * PART1) splits = 8;
  else if (ws_size >= BASE + 4 * PART1) splits = 4;
  else if (ws_size >= BASE + 2 * PART1) splits = 2;

  k_dw_prep<<<3, 128, 0, stream>>>(
      (const float*)d_in[1],  (const float*)d_in[2],  (const float*)d_in[3],
      (const float*)d_in[4],  (const float*)d_in[5],
      (const float*)d_in[7],  (const float*)d_in[8],  (const float*)d_in[9],
      (const float*)d_in[10], (const float*)d_in[11],
      (const float*)d_in[13], (const float*)d_in[14], (const float*)d_in[15],
      (const float*)d_in[16], (const float*)d_in[17], dwf, bfl);

  k_gate_prep<<<1, 128, 0, stream>>>(
      (const float*)d_in[24], (const float*)d_in[19], (const float*)d_in[20],
      (const float*)d_in[21], (const float*)d_in[22], (const float*)d_in[23], Gt, c0);

  k_wg<<<dim3(8, 8), 256, 0, stream>>>((const float*)d_in[6], Gt, WgF);

  k_pack<<<64, 256, 0, stream>>>((const float*)d_in[6], (const float*)d_in[12],
                                 (const float*)d_in[18], (const float*)d_in[25],
                                 Wpk, Opk);
  k_gpack<<<8, 256, 0, stream>>>(WgF, Gpk);

  if (splits > 0) {
    k_kat2<<<dim3(splits, NHEAD), 256, 0, stream>>>(x, dwf, bfl, Wpk, part16, kat, 0);
    k_red<<<NHEAD, 256, 0, stream>>>(part16, katpk, splits);
  } else {
    hipMemsetAsync(kat, 0, (size_t)NHEAD * DIMC * DIMC * 4, stream);
    k_kat2<<<dim3(4, NHEAD), 256, 0, stream>>>(x, dwf, bfl, Wpk, part16, kat, 1);
    k_katpk<<<NHEAD, 256, 0, stream>>>(kat, katpk);
  }
  k_out2<<<dim3(XLEN / TX, BATCH), 256, 0, stream>>>(x, dwf, bfl, Wpk, Gpk, katpk,
                                                     Opk, c0, (const float*)d_in[26],
                                                     (float*)d_out);
}

// Round 6
// 637.533 us; speedup vs baseline: 2.1077x; 2.0419x over previous
//
#include <hip/hip_runtime.h>
#include <hip/hip_bf16.h>

#define DIMC   128
#define HEADS  8
#define BATCH  8
#define XLEN   4096
#define NHEAD  64
#define EPSV   1e-5f
#define SCALEF 0.08838834764831845f   // 128^-0.5
#define TX     64
#define KSPL   4                       // phase-2 x-splits

typedef __attribute__((ext_vector_type(8))) short bf16x8;
typedef __attribute__((ext_vector_type(4))) float f32x4;
#define MFMA(a,b,c) __builtin_amdgcn_mfma_f32_16x16x32_bf16((a),(b),(c),0,0,0)

__device__ __forceinline__ short f2bf(float f) {
  union { float f; unsigned u; } v; v.f = f;
  return (short)((v.u + 0x7fffu + ((v.u >> 16) & 1u)) >> 16);
}
__device__ __forceinline__ float bf2f(short h) {
  union { unsigned u; float f; } v; v.u = ((unsigned)(unsigned short)h) << 16;
  return v.f;
}
__device__ __forceinline__ unsigned pk2(float a, float b) {
  return (unsigned)(unsigned short)f2bf(a) | ((unsigned)(unsigned short)f2bf(b) << 16);
}

// LDS fragment loads. Row-major bf16 tiles, XOR-swizzled: byte ^= (row&7)<<4.
// ldY: row stride 256 B; ldT: row stride 128 B.
__device__ __forceinline__ bf16x8 ldY(const short* Y, int row, int kcb) {
  return *(const bf16x8*)((const char*)Y + row*256 + (kcb ^ ((row&7)<<4)));
}
__device__ __forceinline__ bf16x8 ldT(const short* Y, int row, int kcb) {
  return *(const bf16x8*)((const char*)Y + row*128 + (kcb ^ ((row&7)<<4)));
}

// ---------------------------------------------------------------------------
// prep kernels
// ---------------------------------------------------------------------------
__global__ void k_dw_prep(const float* dw0, const float* g0, const float* b0, const float* m0, const float* v0,
                          const float* dw1, const float* g1, const float* b1, const float* m1, const float* v1,
                          const float* dw2, const float* g2, const float* b2, const float* m2, const float* v2,
                          float* __restrict__ dwf, float* __restrict__ bfl) {
  int p = blockIdx.x, c = threadIdx.x;
  const float* dw = p == 0 ? dw0 : p == 1 ? dw1 : dw2;
  const float* g  = p == 0 ? g0  : p == 1 ? g1  : g2;
  const float* bb = p == 0 ? b0  : p == 1 ? b1  : b2;
  const float* m  = p == 0 ? m0  : p == 1 ? m1  : m2;
  const float* vv = p == 0 ? v0  : p == 1 ? v1  : v2;
  float a = g[c] * rsqrtf(vv[c] + EPSV);
  dwf[(p * DIMC + c) * 3 + 0] = dw[c * 3 + 0] * a;
  dwf[(p * DIMC + c) * 3 + 1] = dw[c * 3 + 1] * a;
  dwf[(p * DIMC + c) * 3 + 2] = dw[c * 3 + 2] * a;
  bfl[p * DIMC + c] = bb[c] - m[c] * a;
}

__global__ void k_gate_prep(const float* __restrict__ gt_pw, const float* __restrict__ gt_dw,
                            const float* __restrict__ gt_g, const float* __restrict__ gt_b,
                            const float* __restrict__ gt_m, const float* __restrict__ gt_v,
                            float* __restrict__ Gt, float* __restrict__ c0) {
  int d = threadIdx.x;
  float s = 0.f;
  for (int i = 0; i < DIMC; ++i) {
    float a  = gt_g[i] * rsqrtf(gt_v[i] + EPSV);
    float w1 = gt_dw[i] * a;
    float w0 = gt_b[i] - gt_m[i] * a;
    float pw = gt_pw[d * DIMC + i];
    Gt[i * DIMC + d] = pw * w1;
    s += pw * w0;
  }
  c0[d] = s;
}

__global__ void k_wg(const float* __restrict__ q_pw, const float* __restrict__ Gt,
                     float* __restrict__ WgF) {
  const int h = blockIdx.x, cb = blockIdx.y, t = threadIdx.x;
  const int c = cb * 16 + (t >> 4);
  const int e0 = (t & 15) * 8;
  float acc[8] = {0.f,0.f,0.f,0.f,0.f,0.f,0.f,0.f};
  for (int d = 0; d < DIMC; ++d) {
    float wq = q_pw[((size_t)(h * DIMC + d)) * DIMC + c];
    const float* gr = Gt + d * DIMC + e0;
    #pragma unroll
    for (int j = 0; j < 8; ++j) acc[j] += wq * gr[j];
  }
  float* out = WgF + ((size_t)h * DIMC + c) * DIMC + e0;
  #pragma unroll
  for (int j = 0; j < 8; ++j) out[j] = acc[j];
}

__global__ void k_pack(const float* __restrict__ q_pw, const float* __restrict__ k_pw,
                       const float* __restrict__ v_pw, const float* __restrict__ out_w,
                       short* __restrict__ Wpk, short* __restrict__ Opk) {
  const int blk = blockIdx.x, t = threadIdx.x;
  if (blk < 48) {
    const int p = blk / 16, h = (blk / 2) & 7, hl = blk & 1;
    const float* pw = p == 0 ? q_pw : p == 1 ? k_pw : v_pw;
    short* dst = Wpk + (size_t)((p * 8 + h) * 2 + hl) * 16384;
    for (int s = t; s < 2048; s += 256) {
      const int l = s & 63, kt = (s >> 6) >> 3, nt = (s >> 6) & 7;
      const int o = h * DIMC + nt * 16 + (l & 15);
      const int cb = kt * 32 + (l >> 4) * 8;
      #pragma unroll
      for (int j = 0; j < 8; ++j) {
        float wv = pw[(size_t)o * DIMC + cb + j];
        short hi = f2bf(wv);
        dst[s * 8 + j] = (hl == 0) ? hi : f2bf(wv - bf2f(hi));
      }
    }
  } else {
    const int m = blk - 48, h = m >> 1, hl = m & 1;
    short* dst = Opk + (size_t)(h * 2 + hl) * 16384;
    for (int s = t; s < 2048; s += 256) {
      const int l = s & 63, mt = (s >> 6) >> 2, kt = (s >> 6) & 3;
      const int o = mt * 16 + (l & 15);
      const int ib = h * DIMC + kt * 32 + (l >> 4) * 8;
      #pragma unroll
      for (int j = 0; j < 8; ++j) {
        float wv = out_w[(size_t)o * (DIMC * HEADS) + ib + j];
        short hi = f2bf(wv);
        dst[s * 8 + j] = (hl == 0) ? hi : f2bf(wv - bf2f(hi));
      }
    }
  }
}

__global__ void k_gpack(const float* __restrict__ WgF, short* __restrict__ Gpk) {
  const int h = blockIdx.x, t = threadIdx.x;
  const float* src = WgF + (size_t)h * 16384;
  short* dst = Gpk + (size_t)h * 16384;
  for (int s = t; s < 2048; s += 256) {
    const int l = s & 63, kt = (s >> 6) >> 3, nt = (s >> 6) & 7;
    const int cb = kt * 32 + (l >> 4) * 8, e = nt * 16 + (l & 15);
    #pragma unroll
    for (int j = 0; j < 8; ++j) dst[s * 8 + j] = f2bf(src[(size_t)(cb + j) * DIMC + e]);
  }
}

// atomic-fallback path: pack kat (fp32, SCALE applied) -> frag bf16
__global__ void k_katpk(const float* __restrict__ kat, short* __restrict__ katpk) {
  const int n = blockIdx.x, t = threadIdx.x;
  const float* kn = kat + (size_t)n * 16384;
  short* dst = katpk + (size_t)n * 16384;
  for (int s = t; s < 2048; s += 256) {
    const int l = s & 63, kt = (s >> 6) >> 3, nt = (s >> 6) & 7;
    const int db = kt * 32 + (l >> 4) * 8, e = nt * 16 + (l & 15);
    #pragma unroll
    for (int j = 0; j < 8; ++j) dst[s * 8 + j] = f2bf(kn[(size_t)(db + j) * DIMC + e]);
  }
}

// sum `splits` bf16 partial kat tiles, scale, pack frags. grid(64)
__global__ __launch_bounds__(256) void k_red(const short* __restrict__ part16,
                                             short* __restrict__ katpk, int splits) {
  __shared__ float sm[DIMC * DIMC];
  const int n = blockIdx.x, t = threadIdx.x;
  for (int i0 = t * 8; i0 < DIMC * DIMC; i0 += 256 * 8) {
    float a[8] = {0.f,0.f,0.f,0.f,0.f,0.f,0.f,0.f};
    for (int s8 = 0; s8 < splits; ++s8) {
      bf16x8 pv = *(const bf16x8*)&part16[((size_t)(s8 * NHEAD + n)) * 16384 + i0];
      #pragma unroll
      for (int j = 0; j < 8; ++j) a[j] += bf2f(pv[j]);
    }
    #pragma unroll
    for (int j = 0; j < 8; ++j) sm[i0 + j] = a[j] * SCALEF;
  }
  __syncthreads();
  short* dst = katpk + (size_t)n * 16384;
  for (int s = t; s < 2048; s += 256) {
    const int l = s & 63, kt = (s >> 6) >> 3, nt = (s >> 6) & 7;
    const int db = kt * 32 + (l >> 4) * 8, e = nt * 16 + (l & 15);
    #pragma unroll
    for (int j = 0; j < 8; ++j) dst[s * 8 + j] = f2bf(sm[(db + j) * DIMC + e]);
  }
}

// ---------------------------------------------------------------------------
// stage Y tiles: dwconv+BN for two projections -> swizzled bf16 LDS [64 x][128 c]
// ---------------------------------------------------------------------------
__device__ __forceinline__ void stage2(const float* __restrict__ x,
    const float* __restrict__ dwf, const float* __restrict__ bfl,
    int b, int xg0, int t, short* Y0, short* Y1, int p0, int p1)
{
  const int xl = t & 63, cg = t >> 6;
  const int xg = xg0 + xl;
  #pragma unroll
  for (int i = 0; i < 16; ++i) {
    const int c = 2 * (cg + 4 * i);
    float v0[2], v1[2];
    #pragma unroll
    for (int u = 0; u < 2; ++u) {
      const int cc = c + u;
      const float* xr = x + ((size_t)b * DIMC + cc) * XLEN + xg;
      float xm = (xg > 0) ? xr[-1] : 0.f;
      float xc = xr[0];
      float xp = (xg < XLEN - 1) ? xr[1] : 0.f;
      const float* d0 = dwf + (p0 * DIMC + cc) * 3;
      const float* d1 = dwf + (p1 * DIMC + cc) * 3;
      v0[u] = xm * d0[0] + xc * d0[1] + xp * d0[2] + bfl[p0 * DIMC + cc];
      v1[u] = xm * d1[0] + xc * d1[1] + xp * d1[2] + bfl[p1 * DIMC + cc];
    }
    const unsigned off = xl * 256 + ((c * 2) ^ ((xl & 7) << 4));
    *(unsigned*)((char*)Y0 + off) = pk2(v0[0], v0[1]);
    *(unsigned*)((char*)Y1 + off) = pk2(v1[0], v1[1]);
  }
}

// ---------------------------------------------------------------------------
// Phase 1: k_proj — per (x-tile, b): Y once; per head: Q/K GEMM (hi/lo),
// softmax; dump qT[nn][d][x], sT[nn][e][x] (bf16, linear) coalesced.
// grid (64, PB), 256 thr.
// ---------------------------------------------------------------------------
__global__ __launch_bounds__(256) void k_proj(
    const float* __restrict__ x, const float* __restrict__ dwf,
    const float* __restrict__ bfl, const short* __restrict__ Wpk,
    short* __restrict__ qT, short* __restrict__ sT, int b0)
{
  __shared__ __align__(16) short Yq[TX * 128], Yk[TX * 128];
  __shared__ __align__(16) short QT[128 * TX], ST[128 * TX];
  const int t = threadIdx.x, w = t >> 6, l = t & 63;
  const int l15 = l & 15, lq = l >> 4;
  const int b = b0 + blockIdx.y;
  const int x0 = blockIdx.x * TX;

  stage2(x, dwf, bfl, b, x0, t, Yq, Yk, 0, 1);
  __syncthreads();

  for (int h = 0; h < HEADS; ++h) {
    const int nn = blockIdx.y * HEADS + h;
    const short* WqHi = Wpk + (size_t)((0 * 8 + h) * 2 + 0) * 16384;
    const short* WqLo = Wpk + (size_t)((0 * 8 + h) * 2 + 1) * 16384;
    const short* WkHi = Wpk + (size_t)((1 * 8 + h) * 2 + 0) * 16384;
    const short* WkLo = Wpk + (size_t)((1 * 8 + h) * 2 + 1) * 16384;

    // Q GEMM (weights hi+lo)
    f32x4 qa[8];
    #pragma unroll
    for (int j = 0; j < 8; ++j) qa[j] = {0.f, 0.f, 0.f, 0.f};
    #pragma unroll
    for (int kt = 0; kt < 4; ++kt) {
      bf16x8 a = ldY(Yq, w * 16 + l15, kt * 64 + lq * 16);
      #pragma unroll
      for (int nt = 0; nt < 8; ++nt) {
        bf16x8 bh = *(const bf16x8*)&WqHi[(kt * 8 + nt) * 512 + l * 8];
        bf16x8 bl = *(const bf16x8*)&WqLo[(kt * 8 + nt) * 512 + l * 8];
        qa[nt] = MFMA(a, bh, qa[nt]);
        qa[nt] = MFMA(a, bl, qa[nt]);
      }
    }
    #pragma unroll
    for (int nt = 0; nt < 8; ++nt) {
      const int d = nt * 16 + l15;
      #pragma unroll
      for (int rp = 0; rp < 2; ++rp) {
        const int x2 = w * 16 + lq * 4 + rp * 2;
        *(unsigned*)((char*)QT + d * 128 + ((x2 * 2) ^ ((d & 7) << 4))) =
            pk2(qa[nt][rp * 2], qa[nt][rp * 2 + 1]);
      }
    }

    // K GEMM (weights hi+lo)
    #pragma unroll
    for (int j = 0; j < 8; ++j) qa[j] = {0.f, 0.f, 0.f, 0.f};
    #pragma unroll
    for (int kt = 0; kt < 4; ++kt) {
      bf16x8 a = ldY(Yk, w * 16 + l15, kt * 64 + lq * 16);
      #pragma unroll
      for (int nt = 0; nt < 8; ++nt) {
        bf16x8 bh = *(const bf16x8*)&WkHi[(kt * 8 + nt) * 512 + l * 8];
        bf16x8 bl = *(const bf16x8*)&WkLo[(kt * 8 + nt) * 512 + l * 8];
        qa[nt] = MFMA(a, bh, qa[nt]);
        qa[nt] = MFMA(a, bl, qa[nt]);
      }
    }
    // in-register row softmax over e
    float inv[4];
    #pragma unroll
    for (int r = 0; r < 4; ++r) {
      float m = qa[0][r];
      #pragma unroll
      for (int nt = 1; nt < 8; ++nt) m = fmaxf(m, qa[nt][r]);
      m = fmaxf(m, __shfl_xor(m, 1)); m = fmaxf(m, __shfl_xor(m, 2));
      m = fmaxf(m, __shfl_xor(m, 4)); m = fmaxf(m, __shfl_xor(m, 8));
      float s = 0.f;
      #pragma unroll
      for (int nt = 0; nt < 8; ++nt) { float e = __expf(qa[nt][r] - m); qa[nt][r] = e; s += e; }
      s += __shfl_xor(s, 1); s += __shfl_xor(s, 2); s += __shfl_xor(s, 4); s += __shfl_xor(s, 8);
      inv[r] = 1.f / s;
    }
    #pragma unroll
    for (int nt = 0; nt < 8; ++nt) {
      const int e = nt * 16 + l15;
      #pragma unroll
      for (int rp = 0; rp < 2; ++rp) {
        const int x2 = w * 16 + lq * 4 + rp * 2;
        *(unsigned*)((char*)ST + e * 128 + ((x2 * 2) ^ ((e & 7) << 4))) =
            pk2(qa[nt][rp * 2] * inv[rp * 2], qa[nt][rp * 2 + 1] * inv[rp * 2 + 1]);
      }
    }
    __syncthreads();          // QT/ST complete

    // coalesced dump: thread t handles row r = t>>1, half = t&1 (64 B)
    {
      const int r = t >> 1, half = t & 1;
      const size_t row = ((size_t)nn * DIMC + r) * XLEN + x0 + half * 32;
      #pragma unroll
      for (int i = 0; i < 4; ++i) {
        const int off = r * 128 + (((half * 64) + i * 16) ^ ((r & 7) << 4));
        *(int4*)(qT + row + i * 8) = *(const int4*)((const char*)QT + off);
        *(int4*)(sT + row + i * 8) = *(const int4*)((const char*)ST + off);
      }
    }
    __syncthreads();          // dump reads done before next-h overwrite
  }
}

// ---------------------------------------------------------------------------
// Phase 2: k_katg — kat partial[split][n] = qT-tile^T-free GEMM over x.
// Stages 128d x 128x tiles of qT,sT with pre-swizzled source, MFMA.
// grid (KSPL, PB*8), 256 thr.
// ---------------------------------------------------------------------------
__global__ __launch_bounds__(256) void k_katg(
    const short* __restrict__ qT, const short* __restrict__ sT,
    short* __restrict__ part16, int n0)
{
  __shared__ __align__(16) short QL[128 * 128], SL[128 * 128];   // 32 KB each
  const int t = threadIdx.x, w = t >> 6, l = t & 63;
  const int l15 = l & 15, lq = l >> 4;
  const int nn = blockIdx.y;
  const int n  = n0 + nn;
  const int xbase = blockIdx.x * (XLEN / KSPL);

  f32x4 ka[2][8];
  #pragma unroll
  for (int i = 0; i < 2; ++i)
    #pragma unroll
    for (int j = 0; j < 8; ++j) ka[i][j] = {0.f, 0.f, 0.f, 0.f};

  for (int ch = 0; ch < (XLEN / KSPL) / 128; ++ch) {
    const int x0 = xbase + ch * 128;
    __syncthreads();                     // prev MFMA reads done
    // stage both tiles: idx -> (d = idx>>4, c = idx&15); pre-swizzled src,
    // linear LDS dest; ldY's read swizzle matches.
    #pragma unroll
    for (int R = 0; R < 8; ++R) {
      const int idx = R * 256 + t;
      const int d = idx >> 4, c = idx & 15;
      const size_t rb = (((size_t)nn * DIMC + d) * XLEN + x0) * 2;
      const int  sw = (c * 16) ^ ((d & 7) << 4);
      int4 qv = *(const int4*)((const char*)qT + rb + sw);
      int4 sv = *(const int4*)((const char*)sT + rb + sw);
      *(int4*)((char*)QL + idx * 16) = qv;
      *(int4*)((char*)SL + idx * 16) = sv;
    }
    __syncthreads();
    #pragma unroll
    for (int kt2 = 0; kt2 < 4; ++kt2) {
      bf16x8 a0 = ldY(QL, w * 32 + l15,      kt2 * 64 + lq * 16);
      bf16x8 a1 = ldY(QL, w * 32 + 16 + l15, kt2 * 64 + lq * 16);
      #pragma unroll
      for (int nt = 0; nt < 8; ++nt) {
        bf16x8 bs = ldY(SL, nt * 16 + l15, kt2 * 64 + lq * 16);
        ka[0][nt] = MFMA(a0, bs, ka[0][nt]);
        ka[1][nt] = MFMA(a1, bs, ka[1][nt]);
      }
    }
  }
  short* dst = part16 + ((size_t)(blockIdx.x * NHEAD + n)) * 16384;
  #pragma unroll
  for (int mt = 0; mt < 2; ++mt)
    #pragma unroll
    for (int nt = 0; nt < 8; ++nt)
      #pragma unroll
      for (int r = 0; r < 4; ++r) {
        const int d = w * 32 + mt * 16 + lq * 4 + r;
        const int e = nt * 16 + l15;
        dst[d * DIMC + e] = f2bf(ka[mt][nt][r]);
      }
}

// ---------------------------------------------------------------------------
// Fallback kernel A (round-5): fused recompute kat, bf16 partials or atomics.
// ---------------------------------------------------------------------------
__global__ __launch_bounds__(256) void k_kat2(
    const float* __restrict__ x, const float* __restrict__ dwf,
    const float* __restrict__ bfl, const short* __restrict__ Wpk,
    short* __restrict__ part16, float* __restrict__ kat, int useAtomic)
{
  __shared__ __align__(16) short Yq[TX * 128], Yk[TX * 128];
  __shared__ __align__(16) short QT[128 * TX], ST[128 * TX];
  const int t = threadIdx.x, w = t >> 6, l = t & 63;
  const int l15 = l & 15, lq = l >> 4;
  const int n = blockIdx.y, b = n >> 3, h = n & 7;
  const int xspan = XLEN / gridDim.x;
  const int xbase = blockIdx.x * xspan;
  const int nchunk = xspan / TX;

  const short* WqHi = Wpk + (size_t)((0 * 8 + h) * 2 + 0) * 16384;
  const short* WqLo = Wpk + (size_t)((0 * 8 + h) * 2 + 1) * 16384;
  const short* WkHi = Wpk + (size_t)((1 * 8 + h) * 2 + 0) * 16384;
  const short* WkLo = Wpk + (size_t)((1 * 8 + h) * 2 + 1) * 16384;

  f32x4 ka[2][8];
  #pragma unroll
  for (int i = 0; i < 2; ++i)
    #pragma unroll
    for (int j = 0; j < 8; ++j) ka[i][j] = {0.f, 0.f, 0.f, 0.f};

  for (int ch = 0; ch < nchunk; ++ch) {
    __syncthreads();
    stage2(x, dwf, bfl, b, xbase + ch * TX, t, Yq, Yk, 0, 1);
    __syncthreads();
    f32x4 qa[8];
    #pragma unroll
    for (int j = 0; j < 8; ++j) qa[j] = {0.f, 0.f, 0.f, 0.f};
    #pragma unroll
    for (int kt = 0; kt < 4; ++kt) {
      bf16x8 a = ldY(Yq, w * 16 + l15, kt * 64 + lq * 16);
      #pragma unroll
      for (int nt = 0; nt < 8; ++nt) {
        bf16x8 bh = *(const bf16x8*)&WqHi[(kt * 8 + nt) * 512 + l * 8];
        bf16x8 bl = *(const bf16x8*)&WqLo[(kt * 8 + nt) * 512 + l * 8];
        qa[nt] = MFMA(a, bh, qa[nt]);
        qa[nt] = MFMA(a, bl, qa[nt]);
      }
    }
    #pragma unroll
    for (int nt = 0; nt < 8; ++nt) {
      const int d = nt * 16 + l15;
      #pragma unroll
      for (int rp = 0; rp < 2; ++rp) {
        const int x2 = w * 16 + lq * 4 + rp * 2;
        *(unsigned*)((char*)QT + d * 128 + ((x2 * 2) ^ ((d & 7) << 4))) =
            pk2(qa[nt][rp * 2], qa[nt][rp * 2 + 1]);
      }
    }
    #pragma unroll
    for (int j = 0; j < 8; ++j) qa[j] = {0.f, 0.f, 0.f, 0.f};
    #pragma unroll
    for (int kt = 0; kt < 4; ++kt) {
      bf16x8 a = ldY(Yk, w * 16 + l15, kt * 64 + lq * 16);
      #pragma unroll
      for (int nt = 0; nt < 8; ++nt) {
        bf16x8 bh = *(const bf16x8*)&WkHi[(kt * 8 + nt) * 512 + l * 8];
        bf16x8 bl = *(const bf16x8*)&WkLo[(kt * 8 + nt) * 512 + l * 8];
        qa[nt] = MFMA(a, bh, qa[nt]);
        qa[nt] = MFMA(a, bl, qa[nt]);
      }
    }
    float inv[4];
    #pragma unroll
    for (int r = 0; r < 4; ++r) {
      float m = qa[0][r];
      #pragma unroll
      for (int nt = 1; nt < 8; ++nt) m = fmaxf(m, qa[nt][r]);
      m = fmaxf(m, __shfl_xor(m, 1)); m = fmaxf(m, __shfl_xor(m, 2));
      m = fmaxf(m, __shfl_xor(m, 4)); m = fmaxf(m, __shfl_xor(m, 8));
      float s = 0.f;
      #pragma unroll
      for (int nt = 0; nt < 8; ++nt) { float e = __expf(qa[nt][r] - m); qa[nt][r] = e; s += e; }
      s += __shfl_xor(s, 1); s += __shfl_xor(s, 2); s += __shfl_xor(s, 4); s += __shfl_xor(s, 8);
      inv[r] = 1.f / s;
    }
    #pragma unroll
    for (int nt = 0; nt < 8; ++nt) {
      const int e = nt * 16 + l15;
      #pragma unroll
      for (int rp = 0; rp < 2; ++rp) {
        const int x2 = w * 16 + lq * 4 + rp * 2;
        *(unsigned*)((char*)ST + e * 128 + ((x2 * 2) ^ ((e & 7) << 4))) =
            pk2(qa[nt][rp * 2] * inv[rp * 2], qa[nt][rp * 2 + 1] * inv[rp * 2 + 1]);
      }
    }
    __syncthreads();
    #pragma unroll
    for (int kt2 = 0; kt2 < 2; ++kt2) {
      bf16x8 a0 = ldT(QT, w * 32 + l15,      kt2 * 64 + lq * 16);
      bf16x8 a1 = ldT(QT, w * 32 + 16 + l15, kt2 * 64 + lq * 16);
      #pragma unroll
      for (int nt = 0; nt < 8; ++nt) {
        bf16x8 bs = ldT(ST, nt * 16 + l15, kt2 * 64 + lq * 16);
        ka[0][nt] = MFMA(a0, bs, ka[0][nt]);
        ka[1][nt] = MFMA(a1, bs, ka[1][nt]);
      }
    }
  }
  if (!useAtomic) {
    short* dst = part16 + ((size_t)(blockIdx.x * NHEAD + n)) * 16384;
    #pragma unroll
    for (int mt = 0; mt < 2; ++mt)
      #pragma unroll
      for (int nt = 0; nt < 8; ++nt)
        #pragma unroll
        for (int r = 0; r < 4; ++r) {
          const int d = w * 32 + mt * 16 + lq * 4 + r;
          const int e = nt * 16 + l15;
          dst[d * DIMC + e] = f2bf(ka[mt][nt][r]);
        }
  } else {
    #pragma unroll
    for (int mt = 0; mt < 2; ++mt)
      #pragma unroll
      for (int nt = 0; nt < 8; ++nt)
        #pragma unroll
        for (int r = 0; r < 4; ++r) {
          const int d = w * 32 + mt * 16 + lq * 4 + r;
          const int e = nt * 16 + l15;
          atomicAdd(&kat[((size_t)n * DIMC + d) * DIMC + e], ka[mt][nt][r] * SCALEF);
        }
  }
}

// ---------------------------------------------------------------------------
// Kernel B: per 64-pos tile: recompute Yq,Yv; per head: V & gate GEMMs,
// v@kat, sigmoid-gate combine, final 1024->128 projection (accumulated).
// grid (64, 8), 256 thr.
// ---------------------------------------------------------------------------
__global__ __launch_bounds__(256) void k_out2(
    const float* __restrict__ x, const float* __restrict__ dwf,
    const float* __restrict__ bfl, const short* __restrict__ Wpk,
    const short* __restrict__ Gpk, const short* __restrict__ katpk,
    const short* __restrict__ Opk, const float* __restrict__ c0,
    const float* __restrict__ outb, float* __restrict__ outp)
{
  __shared__ __align__(16) short Yq[TX * 128], Yv[TX * 128];
  __shared__ __align__(16) short Vx[TX * 128], Tn[TX * 128];
  const int t = threadIdx.x, w = t >> 6, l = t & 63;
  const int l15 = l & 15, lq = l >> 4;
  const int b = blockIdx.y;
  const int x0 = blockIdx.x * TX;

  f32x4 oacc[2][4];
  #pragma unroll
  for (int i = 0; i < 2; ++i)
    #pragma unroll
    for (int j = 0; j < 4; ++j) oacc[i][j] = {0.f, 0.f, 0.f, 0.f};
  float c0v[8], obv[2][4];
  #pragma unroll
  for (int nt = 0; nt < 8; ++nt) c0v[nt] = c0[nt * 16 + l15];
  #pragma unroll
  for (int mt = 0; mt < 2; ++mt)
    #pragma unroll
    for (int r = 0; r < 4; ++r) obv[mt][r] = outb[w * 32 + mt * 16 + lq * 4 + r];

  stage2(x, dwf, bfl, b, x0, t, Yq, Yv, 0, 2);
  __syncthreads();

  for (int h = 0; h < HEADS; ++h) {
    const int n = b * HEADS + h;
    const short* WvHi = Wpk + (size_t)((2 * 8 + h) * 2 + 0) * 16384;
    const short* WvLo = Wpk + (size_t)((2 * 8 + h) * 2 + 1) * 16384;
    const short* Wg   = Gpk + (size_t)h * 16384;
    const short* Kp   = katpk + (size_t)n * 16384;

    f32x4 va[8], ga[8];
    #pragma unroll
    for (int j = 0; j < 8; ++j) { va[j] = {0.f,0.f,0.f,0.f}; ga[j] = {0.f,0.f,0.f,0.f}; }
    #pragma unroll
    for (int kt = 0; kt < 4; ++kt) {
      bf16x8 aV = ldY(Yv, w * 16 + l15, kt * 64 + lq * 16);
      bf16x8 aQ = ldY(Yq, w * 16 + l15, kt * 64 + lq * 16);
      #pragma unroll
      for (int nt = 0; nt < 8; ++nt) {
        bf16x8 bh = *(const bf16x8*)&WvHi[(kt * 8 + nt) * 512 + l * 8];
        bf16x8 bl = *(const bf16x8*)&WvLo[(kt * 8 + nt) * 512 + l * 8];
        bf16x8 bg = *(const bf16x8*)&Wg[(kt * 8 + nt) * 512 + l * 8];
        va[nt] = MFMA(aV, bh, va[nt]);
        va[nt] = MFMA(aV, bl, va[nt]);
        ga[nt] = MFMA(aQ, bg, ga[nt]);
      }
    }
    #pragma unroll
    for (int nt = 0; nt < 8; ++nt) {
      const int dd = nt * 16 + l15;
      #pragma unroll
      for (int r = 0; r < 4; ++r) {
        const int xr = w * 16 + lq * 4 + r;
        *(short*)((char*)Vx + xr * 256 + ((dd * 2) ^ ((xr & 7) << 4))) = f2bf(va[nt][r]);
      }
    }
    f32x4 kv[8];
    #pragma unroll
    for (int j = 0; j < 8; ++j) kv[j] = {0.f, 0.f, 0.f, 0.f};
    #pragma unroll
    for (int kt = 0; kt < 4; ++kt) {
      bf16x8 aK = ldY(Vx, w * 16 + l15, kt * 64 + lq * 16);
      #pragma unroll
      for (int nt = 0; nt < 8; ++nt) {
        bf16x8 bk = *(const bf16x8*)&Kp[(kt * 8 + nt) * 512 + l * 8];
        kv[nt] = MFMA(aK, bk, kv[nt]);
      }
    }
    #pragma unroll
    for (int nt = 0; nt < 8; ++nt) {
      const int e = nt * 16 + l15;
      #pragma unroll
      for (int r = 0; r < 4; ++r) {
        const int xr = w * 16 + lq * 4 + r;
        float vv = bf2f(*(const short*)((const char*)Vx + xr * 256 + ((e * 2) ^ ((xr & 7) << 4))));
        float g = ga[nt][r] + c0v[nt];
        float sig = 1.f / (1.f + __expf(-g));
        *(short*)((char*)Tn + xr * 256 + ((e * 2) ^ ((xr & 7) << 4))) = f2bf(kv[nt][r] + sig * vv);
      }
    }
    __syncthreads();
    const short* OHi = Opk + (size_t)(h * 2 + 0) * 16384;
    const short* OLo = Opk + (size_t)(h * 2 + 1) * 16384;
    #pragma unroll
    for (int kt = 0; kt < 4; ++kt) {
      bf16x8 a0h = *(const bf16x8*)&OHi[((w * 2 + 0) * 4 + kt) * 512 + l * 8];
      bf16x8 a1h = *(const bf16x8*)&OHi[((w * 2 + 1) * 4 + kt) * 512 + l * 8];
      bf16x8 a0l = *(const bf16x8*)&OLo[((w * 2 + 0) * 4 + kt) * 512 + l * 8];
      bf16x8 a1l = *(const bf16x8*)&OLo[((w * 2 + 1) * 4 + kt) * 512 + l * 8];
      #pragma unroll
      for (int nt4 = 0; nt4 < 4; ++nt4) {
        bf16x8 bt = ldY(Tn, nt4 * 16 + l15, kt * 64 + lq * 16);
        oacc[0][nt4] = MFMA(a0h, bt, oacc[0][nt4]);
        oacc[0][nt4] = MFMA(a0l, bt, oacc[0][nt4]);
        oacc[1][nt4] = MFMA(a1h, bt, oacc[1][nt4]);
        oacc[1][nt4] = MFMA(a1l, bt, oacc[1][nt4]);
      }
    }
    __syncthreads();
  }
  #pragma unroll
  for (int mt = 0; mt < 2; ++mt)
    #pragma unroll
    for (int nt4 = 0; nt4 < 4; ++nt4)
      #pragma unroll
      for (int r = 0; r < 4; ++r) {
        const int o = w * 32 + mt * 16 + lq * 4 + r;
        const int xx = x0 + nt4 * 16 + l15;
        outp[((size_t)b * DIMC + o) * XLEN + xx] = oacc[mt][nt4][r] + obv[mt][r];
      }
}

// ---------------------------------------------------------------------------
extern "C" void kernel_launch(void* const* d_in, const int* in_sizes, int n_in,
                              void* d_out, int out_size, void* d_ws, size_t ws_size,
                              hipStream_t stream) {
  (void)in_sizes; (void)n_in; (void)out_size;
  const float* x = (const float*)d_in[0];
  // q: 1..6, k: 7..12, v: 13..18 (dw,g,b,m,v,pw), gt: 19..24, out_w:25, out_b:26

  char* ws = (char*)d_ws;
  short* katpk = (short*)(ws);                       // 2 MB
  short* Wpk   = (short*)(ws + 2097152);             // 1.5 MB
  short* Opk   = (short*)(ws + 3670016);             // 512 KB
  short* Gpk   = (short*)(ws + 4194304);             // 256 KB
  float* WgF   = (float*)(ws + 4456448);             // 512 KB
  float* Gt    = (float*)(ws + 4980736);             // 64 KB
  float* c0    = (float*)(ws + 5046272);             // 512 B
  float* dwf   = (float*)(ws + 5046784);             // 4.6 KB
  float* bfl   = (float*)(ws + 5051392);             // 1.5 KB
  constexpr size_t BASE = 5052928;
  // part16 for KSPL=4 splits (8 MB) lives at BASE; qT/sT after it.
  constexpr size_t PARTB = (size_t)KSPL * NHEAD * 16384 * 2;   // 8,388,608
  short* part16 = (short*)(ws + BASE);
  float* kat    = (float*)(ws + BASE);               // atomic last-resort alias
  constexpr size_t QTOFF = BASE + PARTB;             // 13,441,536
  short* qT = (short*)(ws + QTOFF);
  constexpr size_t PASS1 = (size_t)HEADS * DIMC * XLEN * 2;    // 8 MB per b per tensor

  // choose PB (b's per pass): need QTOFF + PB*PASS1*2 bytes
  int PB = 0;
  if      (ws_size >= QTOFF + 8 * PASS1 * 2) PB = 8;
  else if (ws_size >= QTOFF + 4 * PASS1 * 2) PB = 4;
  else if (ws_size >= QTOFF + 2 * PASS1 * 2) PB = 2;
  else if (ws_size >= QTOFF + 1 * PASS1 * 2) PB = 1;

  k_dw_prep<<<3, 128, 0, stream>>>(
      (const float*)d_in[1],  (const float*)d_in[2],  (const float*)d_in[3],
      (const float*)d_in[4],  (const float*)d_in[5],
      (const float*)d_in[7],  (const float*)d_in[8],  (const float*)d_in[9],
      (const float*)d_in[10], (const float*)d_in[11],
      (const float*)d_in[13], (const float*)d_in[14], (const float*)d_in[15],
      (const float*)d_in[16], (const float*)d_in[17], dwf, bfl);

  k_gate_prep<<<1, 128, 0, stream>>>(
      (const float*)d_in[24], (const float*)d_in[19], (const float*)d_in[20],
      (const float*)d_in[21], (const float*)d_in[22], (const float*)d_in[23], Gt, c0);

  k_wg<<<dim3(8, 8), 256, 0, stream>>>((const float*)d_in[6], Gt, WgF);

  k_pack<<<64, 256, 0, stream>>>((const float*)d_in[6], (const float*)d_in[12],
                                 (const float*)d_in[18], (const float*)d_in[25],
                                 Wpk, Opk);
  k_gpack<<<8, 256, 0, stream>>>(WgF, Gpk);

  if (PB > 0) {
    short* sT = qT + (size_t)PB * PASS1;   // elements (shorts): PASS1 counts bytes/2? no:
    // PASS1 is BYTES per b per tensor; qT/sT are short*: convert.
    sT = (short*)((char*)qT + (size_t)PB * PASS1);
    for (int b0 = 0; b0 < BATCH; b0 += PB) {
      k_proj<<<dim3(XLEN / TX, PB), 256, 0, stream>>>(x, dwf, bfl, Wpk, qT, sT, b0);
      k_katg<<<dim3(KSPL, PB * HEADS), 256, 0, stream>>>(qT, sT, part16, b0 * HEADS);
    }
    k_red<<<NHEAD, 256, 0, stream>>>(part16, katpk, KSPL);
  } else if (ws_size >= BASE + 2 * (size_t)NHEAD * 16384 * 2) {
    // round-5 fallback: bf16 partials, 2 splits
    k_kat2<<<dim3(2, NHEAD), 256, 0, stream>>>(x, dwf, bfl, Wpk, part16, kat, 0);
    k_red<<<NHEAD, 256, 0, stream>>>(part16, katpk, 2);
  } else {
    hipMemsetAsync(kat, 0, (size_t)NHEAD * DIMC * DIMC * 4, stream);
    k_kat2<<<dim3(4, NHEAD), 256, 0, stream>>>(x, dwf, bfl, Wpk, part16, kat, 1);
    k_katpk<<<NHEAD, 256, 0, stream>>>(kat, katpk);
  }
  k_out2<<<dim3(XLEN / TX, BATCH), 256, 0, stream>>>(x, dwf, bfl, Wpk, Gpk, katpk,
                                                     Opk, c0, (const float*)d_in[26],
                                                     (float*)d_out);
}